// Round 1
// baseline (907.966 us; speedup 1.0000x reference)
//
#include <hip/hip_runtime.h>
#include <stdint.h>

// Problem: B=16, C=64, H=W=128. fp32 in/out.
#define NB   16
#define NCH  64
#define HH   128
#define NPOS (HH*HH)        // 16384 spatial positions
#define LSTR 136            // LDS row stride in bf16 elems: 16B-aligned rows, 4-bank row skew
#define LELEM (HH*LSTR)     // 17408 ushorts per staged 128x128 matrix

__device__ __forceinline__ float asf(unsigned int u){ return __uint_as_float(u); }
__device__ __forceinline__ float bf2f(unsigned short u){ return __uint_as_float(((unsigned int)u)<<16); }
__device__ __forceinline__ unsigned short f2bf(float f){
  unsigned int u = __float_as_uint(f);
  u += 0x7FFFu + ((u>>16)&1u);          // RNE; inputs finite
  return (unsigned short)(u>>16);
}

// ---------------- Kernel 1: Q/K/V = relu(conv1x1) -> bf16 -----------------
// grid (32 ptiles, 16 b, 3 m). Each thread: 2 positions x 64 out-channels.
__global__ __launch_bounds__(256) void rc_conv_qkv(
    const float* __restrict__ x, const float* __restrict__ att,
    const float* __restrict__ w0, const float* __restrict__ b0,
    const float* __restrict__ w1, const float* __restrict__ b1,
    const float* __restrict__ w2, const float* __restrict__ b2,
    unsigned short* __restrict__ Qb, unsigned short* __restrict__ Kb,
    unsigned short* __restrict__ Vb)
{
  __shared__ float wT[NCH*NCH];   // wT[c_in][c_out]
  __shared__ float bias[NCH];
  const int m  = blockIdx.z;
  const int b  = blockIdx.y;
  const int pt = blockIdx.x;
  const int tid = threadIdx.x;
  const float* w   = (m==0) ? w0 : (m==1 ? w1 : w2);
  const float* bb  = (m==0) ? b0 : (m==1 ? b1 : b2);
  const float* src = (m==1) ? att : x;
  unsigned short* dst = (m==0) ? Qb : (m==1 ? Kb : Vb);

  for (int i = tid; i < NCH*NCH; i += 256){
    int c = i >> 6, cp = i & 63;
    wT[cp*NCH + c] = w[i];        // transpose: broadcast-friendly reads below
  }
  if (tid < NCH) bias[tid] = bb[tid];
  __syncthreads();

  const size_t p0 = (size_t)pt*512 + tid;
  const size_t p1 = p0 + 256;
  const float* s0 = src + (size_t)b*NCH*NPOS;

  float acc0[NCH], acc1[NCH];
  #pragma unroll
  for (int c=0;c<NCH;c++){ acc0[c]=0.f; acc1[c]=0.f; }

  #pragma unroll 2
  for (int cp=0; cp<NCH; cp++){
    float xv0 = s0[(size_t)cp*NPOS + p0];
    float xv1 = s0[(size_t)cp*NPOS + p1];
    const float4* wrow = (const float4*)&wT[cp*NCH];
    #pragma unroll
    for (int cg=0; cg<16; cg++){
      float4 wv = wrow[cg];
      acc0[cg*4+0] = fmaf(wv.x, xv0, acc0[cg*4+0]);
      acc0[cg*4+1] = fmaf(wv.y, xv0, acc0[cg*4+1]);
      acc0[cg*4+2] = fmaf(wv.z, xv0, acc0[cg*4+2]);
      acc0[cg*4+3] = fmaf(wv.w, xv0, acc0[cg*4+3]);
      acc1[cg*4+0] = fmaf(wv.x, xv1, acc1[cg*4+0]);
      acc1[cg*4+1] = fmaf(wv.y, xv1, acc1[cg*4+1]);
      acc1[cg*4+2] = fmaf(wv.z, xv1, acc1[cg*4+2]);
      acc1[cg*4+3] = fmaf(wv.w, xv1, acc1[cg*4+3]);
    }
  }
  #pragma unroll
  for (int c=0;c<NCH;c++){
    float v0 = fmaxf(acc0[c]+bias[c], 0.f);
    float v1 = fmaxf(acc1[c]+bias[c], 0.f);
    size_t base = ((size_t)b*NCH + c)*NPOS;
    dst[base+p0] = f2bf(v0);
    dst[base+p1] = f2bf(v1);
  }
}

// ---------------- Kernel 2: fused per-(b,c) attention ---------------------
// 1024 blocks x 512 threads. LDS: Qs,Ks,VsT,As bf16 [128][136] = 139264 B.
// Thread (r=tid>>2, q=tid&3) owns output row r, column quarter q (32 cols).
__global__ __launch_bounds__(512) void rc_attention(
    const unsigned short* __restrict__ Qb, const unsigned short* __restrict__ Kb,
    const unsigned short* __restrict__ Vb, float* __restrict__ Pf)
{
  extern __shared__ unsigned short lds[];
  unsigned short* Qs  = lds;
  unsigned short* Ks  = lds + LELEM;
  unsigned short* VsT = lds + 2*LELEM;   // V transposed: VsT[j][w] = V[w][j]
  unsigned short* As  = lds + 3*LELEM;   // A1 (row-major), later A2^T

  const int bc = blockIdx.x;
  const size_t gbase = (size_t)bc * NPOS;
  const int tid = threadIdx.x;

  // ---- stage Q,K row-major; V transposed ----
  #pragma unroll
  for (int i=0;i<16;i++){
    int e = 2*tid + 1024*i;              // even, covers [0,16384)
    int row = e >> 7, col = e & 127;
    unsigned int qv = *(const unsigned int*)(Qb + gbase + e);
    unsigned int kv = *(const unsigned int*)(Kb + gbase + e);
    unsigned int vv = *(const unsigned int*)(Vb + gbase + e);
    *(unsigned int*)(Qs + row*LSTR + col) = qv;
    *(unsigned int*)(Ks + row*LSTR + col) = kv;
    VsT[(col  )*LSTR + row] = (unsigned short)(vv & 0xffffu);
    VsT[(col+1)*LSTR + row] = (unsigned short)(vv >> 16);
  }
  __syncthreads();

  const int r  = tid >> 2;
  const int qq = tid & 3;
  const int jbase = qq*32;

  // ---- S1[r][j] = sum_k Q[r,k]*K[j,k]; softmax rows; A1 -> As ----
  float s[32];
  #pragma unroll
  for (int j=0;j<32;j++) s[j]=0.f;
  for (int kc=0; kc<16; kc++){
    uint4 q4 = *(const uint4*)(Qs + r*LSTR + kc*8);
    float qf[8];
    qf[0]=asf(q4.x<<16); qf[1]=asf(q4.x&0xffff0000u);
    qf[2]=asf(q4.y<<16); qf[3]=asf(q4.y&0xffff0000u);
    qf[4]=asf(q4.z<<16); qf[5]=asf(q4.z&0xffff0000u);
    qf[6]=asf(q4.w<<16); qf[7]=asf(q4.w&0xffff0000u);
    #pragma unroll
    for (int j=0;j<32;j++){
      uint4 k4 = *(const uint4*)(Ks + (jbase+j)*LSTR + kc*8);
      float t;
      t  = qf[0]*asf(k4.x<<16) + qf[1]*asf(k4.x&0xffff0000u);
      t += qf[2]*asf(k4.y<<16) + qf[3]*asf(k4.y&0xffff0000u);
      t += qf[4]*asf(k4.z<<16) + qf[5]*asf(k4.z&0xffff0000u);
      t += qf[6]*asf(k4.w<<16) + qf[7]*asf(k4.w&0xffff0000u);
      s[j] += t;
    }
  }
  {
    float mx = s[0];
    #pragma unroll
    for (int j=1;j<32;j++) mx = fmaxf(mx, s[j]);
    mx = fmaxf(mx, __shfl_xor(mx,1));
    mx = fmaxf(mx, __shfl_xor(mx,2));
    float sum = 0.f;
    #pragma unroll
    for (int j=0;j<32;j++){ s[j] = __expf(s[j]-mx); sum += s[j]; }
    sum += __shfl_xor(sum,1);
    sum += __shfl_xor(sum,2);
    float inv = 1.f/sum;
    #pragma unroll
    for (int j=0;j<32;j+=2){
      unsigned int pk = (unsigned int)f2bf(s[j]*inv) | ((unsigned int)f2bf(s[j+1]*inv)<<16);
      *(unsigned int*)(As + r*LSTR + jbase + j) = pk;
    }
  }
  __syncthreads();

  // ---- M[r][j] = sum_w A1[r,w]*V[w,j] = sum_w As[r][w]*VsT[j][w] ----
  float mrow[32];
  #pragma unroll
  for (int j=0;j<32;j++) mrow[j]=0.f;
  for (int wc=0; wc<16; wc++){
    uint4 a4 = *(const uint4*)(As + r*LSTR + wc*8);
    float af[8];
    af[0]=asf(a4.x<<16); af[1]=asf(a4.x&0xffff0000u);
    af[2]=asf(a4.y<<16); af[3]=asf(a4.y&0xffff0000u);
    af[4]=asf(a4.z<<16); af[5]=asf(a4.z&0xffff0000u);
    af[6]=asf(a4.w<<16); af[7]=asf(a4.w&0xffff0000u);
    #pragma unroll
    for (int j=0;j<32;j++){
      uint4 v4 = *(const uint4*)(VsT + (jbase+j)*LSTR + wc*8);
      float t;
      t  = af[0]*asf(v4.x<<16) + af[1]*asf(v4.x&0xffff0000u);
      t += af[2]*asf(v4.y<<16) + af[3]*asf(v4.y&0xffff0000u);
      t += af[4]*asf(v4.z<<16) + af[5]*asf(v4.z&0xffff0000u);
      t += af[6]*asf(v4.w<<16) + af[7]*asf(v4.w&0xffff0000u);
      mrow[j] += t;
    }
  }
  __syncthreads();   // all A1 reads done before As is overwritten with A2^T

  // ---- S2[i=r][j] = sum_h K[h,i]*Q[h,j] (outer-product form); softmax; A2^T -> As ----
  float s2[32];
  #pragma unroll
  for (int j=0;j<32;j++) s2[j]=0.f;
  for (int h=0; h<128; h++){
    float kv = bf2f(Ks[h*LSTR + r]);
    const uint4* qp = (const uint4*)(Qs + h*LSTR + jbase);
    #pragma unroll
    for (int jc=0; jc<4; jc++){
      uint4 q4 = qp[jc];
      s2[jc*8+0] = fmaf(kv, asf(q4.x<<16),          s2[jc*8+0]);
      s2[jc*8+1] = fmaf(kv, asf(q4.x&0xffff0000u),  s2[jc*8+1]);
      s2[jc*8+2] = fmaf(kv, asf(q4.y<<16),          s2[jc*8+2]);
      s2[jc*8+3] = fmaf(kv, asf(q4.y&0xffff0000u),  s2[jc*8+3]);
      s2[jc*8+4] = fmaf(kv, asf(q4.z<<16),          s2[jc*8+4]);
      s2[jc*8+5] = fmaf(kv, asf(q4.z&0xffff0000u),  s2[jc*8+5]);
      s2[jc*8+6] = fmaf(kv, asf(q4.w<<16),          s2[jc*8+6]);
      s2[jc*8+7] = fmaf(kv, asf(q4.w&0xffff0000u),  s2[jc*8+7]);
    }
  }
  {
    float mx = s2[0];
    #pragma unroll
    for (int j=1;j<32;j++) mx = fmaxf(mx, s2[j]);
    mx = fmaxf(mx, __shfl_xor(mx,1));
    mx = fmaxf(mx, __shfl_xor(mx,2));
    float sum = 0.f;
    #pragma unroll
    for (int j=0;j<32;j++){ s2[j] = __expf(s2[j]-mx); sum += s2[j]; }
    sum += __shfl_xor(sum,1);
    sum += __shfl_xor(sum,2);
    float inv = 1.f/sum;
    #pragma unroll
    for (int j=0;j<32;j++){
      As[(jbase+j)*LSTR + r] = f2bf(s2[j]*inv);   // transposed: As[J][i] = A2[i][J]
    }
  }
  __syncthreads();

  // ---- P[r][j] = sum_w M[r,w]*A2[w,j] = sum_w M[r,w]*As[j][w] ----
  // M row r is spread over the 4-lane group; broadcast quarters via __shfl.
  float p[32];
  #pragma unroll
  for (int j=0;j<32;j++) p[j]=0.f;
  #pragma unroll
  for (int wq=0; wq<4; wq++){
    float mv[32];
    #pragma unroll
    for (int wi=0; wi<32; wi++) mv[wi] = __shfl(mrow[wi], wq, 4);
    #pragma unroll
    for (int wc=0; wc<4; wc++){
      #pragma unroll
      for (int j=0;j<32;j++){
        uint4 a4 = *(const uint4*)(As + (jbase+j)*LSTR + wq*32 + wc*8);
        float t;
        t  = mv[wc*8+0]*asf(a4.x<<16) + mv[wc*8+1]*asf(a4.x&0xffff0000u);
        t += mv[wc*8+2]*asf(a4.y<<16) + mv[wc*8+3]*asf(a4.y&0xffff0000u);
        t += mv[wc*8+4]*asf(a4.z<<16) + mv[wc*8+5]*asf(a4.z&0xffff0000u);
        t += mv[wc*8+6]*asf(a4.w<<16) + mv[wc*8+7]*asf(a4.w&0xffff0000u);
        p[j] += t;
      }
    }
  }
  float* pout = Pf + gbase + (size_t)r*HH + jbase;
  #pragma unroll
  for (int j=0;j<32;j+=4){
    float4 v; v.x=p[j]; v.y=p[j+1]; v.z=p[j+2]; v.w=p[j+3];
    *(float4*)(pout + j) = v;
  }
}

// ---------------- Kernel 3: out = relu(conv1x1(P, w3, b3)) fp32 -----------
__global__ __launch_bounds__(256) void rc_conv_out(
    const float* __restrict__ Pf, const float* __restrict__ w3,
    const float* __restrict__ b3, float* __restrict__ out)
{
  __shared__ float wT[NCH*NCH];
  __shared__ float bias[NCH];
  const int b  = blockIdx.y;
  const int pt = blockIdx.x;
  const int tid = threadIdx.x;
  for (int i = tid; i < NCH*NCH; i += 256){
    int c = i >> 6, cp = i & 63;
    wT[cp*NCH + c] = w3[i];
  }
  if (tid < NCH) bias[tid] = b3[tid];
  __syncthreads();

  const size_t p0 = (size_t)pt*512 + tid;
  const size_t p1 = p0 + 256;
  const float* s0 = Pf + (size_t)b*NCH*NPOS;

  float acc0[NCH], acc1[NCH];
  #pragma unroll
  for (int c=0;c<NCH;c++){ acc0[c]=0.f; acc1[c]=0.f; }

  #pragma unroll 2
  for (int cp=0; cp<NCH; cp++){
    float xv0 = s0[(size_t)cp*NPOS + p0];
    float xv1 = s0[(size_t)cp*NPOS + p1];
    const float4* wrow = (const float4*)&wT[cp*NCH];
    #pragma unroll
    for (int cg=0; cg<16; cg++){
      float4 wv = wrow[cg];
      acc0[cg*4+0] = fmaf(wv.x, xv0, acc0[cg*4+0]);
      acc0[cg*4+1] = fmaf(wv.y, xv0, acc0[cg*4+1]);
      acc0[cg*4+2] = fmaf(wv.z, xv0, acc0[cg*4+2]);
      acc0[cg*4+3] = fmaf(wv.w, xv0, acc0[cg*4+3]);
      acc1[cg*4+0] = fmaf(wv.x, xv1, acc1[cg*4+0]);
      acc1[cg*4+1] = fmaf(wv.y, xv1, acc1[cg*4+1]);
      acc1[cg*4+2] = fmaf(wv.z, xv1, acc1[cg*4+2]);
      acc1[cg*4+3] = fmaf(wv.w, xv1, acc1[cg*4+3]);
    }
  }
  #pragma unroll
  for (int c=0;c<NCH;c++){
    float v0 = fmaxf(acc0[c]+bias[c], 0.f);
    float v1 = fmaxf(acc1[c]+bias[c], 0.f);
    size_t base = ((size_t)b*NCH + c)*NPOS;
    out[base+p0] = v0;
    out[base+p1] = v1;
  }
}

extern "C" void kernel_launch(void* const* d_in, const int* in_sizes, int n_in,
                              void* d_out, int out_size, void* d_ws, size_t ws_size,
                              hipStream_t stream)
{
  const float* x   = (const float*)d_in[0];
  const float* att = (const float*)d_in[1];
  const float* w0  = (const float*)d_in[2]; const float* b0 = (const float*)d_in[3];
  const float* w1  = (const float*)d_in[4]; const float* b1 = (const float*)d_in[5];
  const float* w2  = (const float*)d_in[6]; const float* b2 = (const float*)d_in[7];
  const float* w3  = (const float*)d_in[8]; const float* b3 = (const float*)d_in[9];

  const size_t NM = (size_t)NB*NCH*NPOS;          // 16,777,216 elems per matrix
  unsigned short* Qb = (unsigned short*)d_ws;     // bf16, 33.55 MB
  unsigned short* Kb = Qb + NM;
  unsigned short* Vb = Kb + NM;
  float* Pf = (float*)((char*)d_ws + 3*NM*sizeof(unsigned short));  // fp32, 67.1 MB
  float* out = (float*)d_out;

  // allow >64KB dynamic LDS for the attention kernel (gfx950: 160KB/CU)
  (void)hipFuncSetAttribute((const void*)rc_attention,
                            hipFuncAttributeMaxDynamicSharedMemorySize, 4*LELEM*2);

  dim3 g1(32, NB, 3);
  rc_conv_qkv<<<g1, 256, 0, stream>>>(x, att, w0,b0, w1,b1, w2,b2, Qb, Kb, Vb);

  rc_attention<<<dim3(NB*NCH), 512, 4*LELEM*2, stream>>>(Qb, Kb, Vb, Pf);

  dim3 g3(32, NB, 1);
  rc_conv_out<<<g3, 256, 0, stream>>>(Pf, w3, b3, out);
}

// Round 2
// 250.521 us; speedup vs baseline: 3.6243x; 3.6243x over previous
//
#include <hip/hip_runtime.h>
#include <stdint.h>

// Problem: B=16, C=64, H=W=128. fp32 in/out.
#define NB   16
#define NCH  64
#define HH   128
#define NPOS (HH*HH)        // 16384 spatial positions

typedef short bf16x8 __attribute__((ext_vector_type(8)));   // 8 bf16 = 4 VGPRs
typedef float f32x4  __attribute__((ext_vector_type(4)));

__device__ __forceinline__ unsigned short f2bf(float f){
  unsigned int u = __float_as_uint(f);
  u += 0x7FFFu + ((u>>16)&1u);          // RNE; inputs finite
  return (unsigned short)(u>>16);
}

// LDS buffers: 128 rows x 256 bytes (128 bf16 cols), XOR swizzle on byte bits 4-6.
// swz spreads 16 consecutive rows across 8 16B slots (2-way = free, m136).
__device__ __forceinline__ int swz(int row, int cb){
  return cb ^ (((row & 7) ^ ((row >> 3) & 7)) << 4);
}

// ---------------- Kernel 1: Q/K/V = relu(conv1x1) -> bf16 -----------------
__global__ __launch_bounds__(256) void rc_conv_qkv(
    const float* __restrict__ x, const float* __restrict__ att,
    const float* __restrict__ w0, const float* __restrict__ b0,
    const float* __restrict__ w1, const float* __restrict__ b1,
    const float* __restrict__ w2, const float* __restrict__ b2,
    unsigned short* __restrict__ Qb, unsigned short* __restrict__ Kb,
    unsigned short* __restrict__ Vb)
{
  __shared__ float wT[NCH*NCH];   // wT[c_in][c_out]
  __shared__ float bias[NCH];
  const int m  = blockIdx.z;
  const int b  = blockIdx.y;
  const int pt = blockIdx.x;
  const int tid = threadIdx.x;
  const float* w   = (m==0) ? w0 : (m==1 ? w1 : w2);
  const float* bb  = (m==0) ? b0 : (m==1 ? b1 : b2);
  const float* src = (m==1) ? att : x;
  unsigned short* dst = (m==0) ? Qb : (m==1 ? Kb : Vb);

  for (int i = tid; i < NCH*NCH; i += 256){
    int c = i >> 6, cp = i & 63;
    wT[cp*NCH + c] = w[i];
  }
  if (tid < NCH) bias[tid] = bb[tid];
  __syncthreads();

  const size_t p0 = (size_t)pt*512 + tid;
  const size_t p1 = p0 + 256;
  const float* s0 = src + (size_t)b*NCH*NPOS;

  float acc0[NCH], acc1[NCH];
  #pragma unroll
  for (int c=0;c<NCH;c++){ acc0[c]=0.f; acc1[c]=0.f; }

  #pragma unroll 2
  for (int cp=0; cp<NCH; cp++){
    float xv0 = s0[(size_t)cp*NPOS + p0];
    float xv1 = s0[(size_t)cp*NPOS + p1];
    const float4* wrow = (const float4*)&wT[cp*NCH];
    #pragma unroll
    for (int cg=0; cg<16; cg++){
      float4 wv = wrow[cg];
      acc0[cg*4+0] = fmaf(wv.x, xv0, acc0[cg*4+0]);
      acc0[cg*4+1] = fmaf(wv.y, xv0, acc0[cg*4+1]);
      acc0[cg*4+2] = fmaf(wv.z, xv0, acc0[cg*4+2]);
      acc0[cg*4+3] = fmaf(wv.w, xv0, acc0[cg*4+3]);
      acc1[cg*4+0] = fmaf(wv.x, xv1, acc1[cg*4+0]);
      acc1[cg*4+1] = fmaf(wv.y, xv1, acc1[cg*4+1]);
      acc1[cg*4+2] = fmaf(wv.z, xv1, acc1[cg*4+2]);
      acc1[cg*4+3] = fmaf(wv.w, xv1, acc1[cg*4+3]);
    }
  }
  #pragma unroll
  for (int c=0;c<NCH;c++){
    float v0 = fmaxf(acc0[c]+bias[c], 0.f);
    float v1 = fmaxf(acc1[c]+bias[c], 0.f);
    size_t base = ((size_t)b*NCH + c)*NPOS;
    dst[base+p0] = f2bf(v0);
    dst[base+p1] = f2bf(v1);
  }
}

// ---------------- Kernel 2: fused per-(b,c) MFMA attention ----------------
// 1024 blocks x 512 threads (8 waves). LDS = 4 x 32KB swizzled buffers.
// B0: Q rm -> M rm      B1: K rm -> VT rm
// B2: QT rm -> A2T rm   B3: KT rm -> A1 rm
// Products (all mfma_f32_16x16x32_bf16, wave w owns a 16-row strip):
//   P1: S1T = K*Q^T  -> softmax(in-frag j) -> store-transposed = A1 rm
//   P2: S2  = K^T*Q  -> softmax(cross-lane j) -> store-transposed = A2T rm
//   P3: MT  = V^T*A1^T -> store-transposed = M rm (bf16)
//   P4: P   = M*A2 -> global fp32
__global__ __launch_bounds__(512) void rc_attention_mfma(
    const unsigned short* __restrict__ Qb, const unsigned short* __restrict__ Kb,
    const unsigned short* __restrict__ Vb, float* __restrict__ Pf)
{
  extern __shared__ char lds[];
  char* B0 = lds;
  char* B1 = lds + 32768;
  char* B2 = lds + 65536;
  char* B3 = lds + 98304;
  const int tid = threadIdx.x;
  const int l  = tid & 63;
  const int w  = tid >> 6;          // wave 0..7
  const int lq = l >> 4;            // quarter 0..3
  const int lm = l & 15;
  const size_t gbase = (size_t)blockIdx.x * NPOS;

  // ---- V global loads early (held in regs through P1/P2) ----
  uint4 vreg[4];
  #pragma unroll
  for (int i=0;i<4;i++)
    vreg[i] = *(const uint4*)(Vb + gbase + (size_t)(tid + 512*i)*8);

  // ---- stage Q,K row-major + transposed ----
  #pragma unroll
  for (int i=0;i<4;i++){
    int e = (tid + 512*i)*8;
    int row = e >> 7, col = e & 127;
    uint4 q = *(const uint4*)(Qb + gbase + e);
    uint4 k = *(const uint4*)(Kb + gbase + e);
    *(uint4*)(B0 + row*256 + swz(row, col*2)) = q;
    *(uint4*)(B1 + row*256 + swz(row, col*2)) = k;
    unsigned int qd[4] = {q.x,q.y,q.z,q.w};
    unsigned int kd[4] = {k.x,k.y,k.z,k.w};
    #pragma unroll
    for (int u=0;u<8;u++){
      unsigned short qe = (unsigned short)(qd[u>>1] >> (16*(u&1)));
      unsigned short ke = (unsigned short)(kd[u>>1] >> (16*(u&1)));
      int tr = col + u;             // T-row = original col
      *(unsigned short*)(B2 + tr*256 + swz(tr, row*2)) = qe;
      *(unsigned short*)(B3 + tr*256 + swz(tr, row*2)) = ke;
    }
  }
  __syncthreads();

  // ---- P1: S1T = K * Q^T (wave owns S1T col strip r in [16w,16w+16)) ----
  f32x4 acc1[8];
  #pragma unroll
  for (int t=0;t<8;t++) acc1[t] = (f32x4){0.f,0.f,0.f,0.f};
  {
    bf16x8 bq[4];                   // B-frag cache: Q rows r=16w+lm
    #pragma unroll
    for (int kk=0;kk<4;kk++){
      int r = 16*w + lm;
      bq[kk] = *(const bf16x8*)(B0 + r*256 + swz(r, kk*64 + lq*16));
    }
    #pragma unroll
    for (int kk=0;kk<4;kk++){
      #pragma unroll
      for (int jt=0;jt<8;jt++){
        int jr = jt*16 + lm;        // A-frag: K row j
        bf16x8 ak = *(const bf16x8*)(B1 + jr*256 + swz(jr, kk*64 + lq*16));
        acc1[jt] = __builtin_amdgcn_mfma_f32_16x16x32_bf16(ak, bq[kk], acc1[jt], 0,0,0);
      }
    }
  }
  // softmax over j (S1T rows): 32 in-lane values + xor16/xor32
  unsigned int a1p[8][2];
  {
    float mx = -1e30f;
    #pragma unroll
    for (int t=0;t<8;t++){
      mx = fmaxf(mx, fmaxf(fmaxf(acc1[t][0], acc1[t][1]), fmaxf(acc1[t][2], acc1[t][3])));
    }
    mx = fmaxf(mx, __shfl_xor(mx, 16));
    mx = fmaxf(mx, __shfl_xor(mx, 32));
    float sum = 0.f;
    #pragma unroll
    for (int t=0;t<8;t++){
      #pragma unroll
      for (int r4=0;r4<4;r4++){ float e = __expf(acc1[t][r4] - mx); acc1[t][r4] = e; sum += e; }
    }
    sum += __shfl_xor(sum, 16);
    sum += __shfl_xor(sum, 32);
    float inv = 1.f/sum;
    #pragma unroll
    for (int t=0;t<8;t++){
      a1p[t][0] = (unsigned int)f2bf(acc1[t][0]*inv) | ((unsigned int)f2bf(acc1[t][1]*inv)<<16);
      a1p[t][1] = (unsigned int)f2bf(acc1[t][2]*inv) | ((unsigned int)f2bf(acc1[t][3]*inv)<<16);
    }
  }

  // ---- P2: S2 = K^T * Q (wave owns S2 row strip i in [16w,16w+16)) ----
  f32x4 acc2[8];
  #pragma unroll
  for (int t=0;t<8;t++) acc2[t] = (f32x4){0.f,0.f,0.f,0.f};
  {
    bf16x8 akt[4];                  // A-frag cache: KT rows i=16w+lm
    #pragma unroll
    for (int kk=0;kk<4;kk++){
      int ir = 16*w + lm;
      akt[kk] = *(const bf16x8*)(B3 + ir*256 + swz(ir, kk*64 + lq*16));
    }
    #pragma unroll
    for (int kk=0;kk<4;kk++){
      #pragma unroll
      for (int ct=0;ct<8;ct++){
        int jr = ct*16 + lm;        // B-frag: QT row j
        bf16x8 bqt = *(const bf16x8*)(B2 + jr*256 + swz(jr, kk*64 + lq*16));
        acc2[ct] = __builtin_amdgcn_mfma_f32_16x16x32_bf16(akt[kk], bqt, acc2[ct], 0,0,0);
      }
    }
  }
  // softmax over j (S2 cols): per-reg in-lane over 8 tiles + xor1..8
  unsigned int a2p[8][2];
  {
    float m0=-1e30f, m1=-1e30f, m2=-1e30f, m3=-1e30f;
    #pragma unroll
    for (int t=0;t<8;t++){
      m0 = fmaxf(m0, acc2[t][0]); m1 = fmaxf(m1, acc2[t][1]);
      m2 = fmaxf(m2, acc2[t][2]); m3 = fmaxf(m3, acc2[t][3]);
    }
    #pragma unroll
    for (int d=1; d<16; d<<=1){
      m0 = fmaxf(m0, __shfl_xor(m0,d)); m1 = fmaxf(m1, __shfl_xor(m1,d));
      m2 = fmaxf(m2, __shfl_xor(m2,d)); m3 = fmaxf(m3, __shfl_xor(m3,d));
    }
    float s0=0.f, s1=0.f, s2=0.f, s3=0.f;
    #pragma unroll
    for (int t=0;t<8;t++){
      float e0 = __expf(acc2[t][0]-m0); acc2[t][0]=e0; s0 += e0;
      float e1 = __expf(acc2[t][1]-m1); acc2[t][1]=e1; s1 += e1;
      float e2 = __expf(acc2[t][2]-m2); acc2[t][2]=e2; s2 += e2;
      float e3 = __expf(acc2[t][3]-m3); acc2[t][3]=e3; s3 += e3;
    }
    #pragma unroll
    for (int d=1; d<16; d<<=1){
      s0 += __shfl_xor(s0,d); s1 += __shfl_xor(s1,d);
      s2 += __shfl_xor(s2,d); s3 += __shfl_xor(s3,d);
    }
    float i0=1.f/s0, i1=1.f/s1, i2=1.f/s2, i3=1.f/s3;
    #pragma unroll
    for (int t=0;t<8;t++){
      a2p[t][0] = (unsigned int)f2bf(acc2[t][0]*i0) | ((unsigned int)f2bf(acc2[t][1]*i1)<<16);
      a2p[t][1] = (unsigned int)f2bf(acc2[t][2]*i2) | ((unsigned int)f2bf(acc2[t][3]*i3)<<16);
    }
  }

  __syncthreads();   // all P1/P2 LDS reads complete -> buffers reusable

  // ---- write A1 -> B3 (rm), A2T -> B2 (rm), VT -> B1 ----
  {
    int r = 16*w + lm;
    #pragma unroll
    for (int t=0;t<8;t++)
      *(uint2*)(B3 + r*256 + swz(r, t*32 + lq*8)) = make_uint2(a1p[t][0], a1p[t][1]);
  }
  #pragma unroll
  for (int t=0;t<8;t++){
    int jr = t*16 + lm;
    *(uint2*)(B2 + jr*256 + swz(jr, 32*w + lq*8)) = make_uint2(a2p[t][0], a2p[t][1]);
  }
  #pragma unroll
  for (int i=0;i<4;i++){
    int e = (tid + 512*i)*8;
    int row = e>>7, col = e&127;
    unsigned int vd[4] = {vreg[i].x, vreg[i].y, vreg[i].z, vreg[i].w};
    #pragma unroll
    for (int u=0;u<8;u++){
      unsigned short ve = (unsigned short)(vd[u>>1] >> (16*(u&1)));
      int tr = col + u;
      *(unsigned short*)(B1 + tr*256 + swz(tr, row*2)) = ve;
    }
  }
  __syncthreads();

  // ---- P3: MT = V^T * A1^T (wave owns MT row strip j in [16w,16w+16)) ----
  f32x4 acc3[8];
  #pragma unroll
  for (int t=0;t<8;t++) acc3[t] = (f32x4){0.f,0.f,0.f,0.f};
  {
    bf16x8 av[4];                   // A-frag cache: VT rows j=16w+lm
    #pragma unroll
    for (int kk=0;kk<4;kk++){
      int jr = 16*w + lm;
      av[kk] = *(const bf16x8*)(B1 + jr*256 + swz(jr, kk*64 + lq*16));
    }
    #pragma unroll
    for (int kk=0;kk<4;kk++){
      #pragma unroll
      for (int rt=0;rt<8;rt++){
        int rr = rt*16 + lm;        // B-frag: A1 row r
        bf16x8 ba = *(const bf16x8*)(B3 + rr*256 + swz(rr, kk*64 + lq*16));
        acc3[rt] = __builtin_amdgcn_mfma_f32_16x16x32_bf16(av[kk], ba, acc3[rt], 0,0,0);
      }
    }
  }
  // store M (bf16) rm -> B0 (Q dead)
  #pragma unroll
  for (int rt=0;rt<8;rt++){
    int rr = rt*16 + lm;
    unsigned int p0 = (unsigned int)f2bf(acc3[rt][0]) | ((unsigned int)f2bf(acc3[rt][1])<<16);
    unsigned int p1 = (unsigned int)f2bf(acc3[rt][2]) | ((unsigned int)f2bf(acc3[rt][3])<<16);
    *(uint2*)(B0 + rr*256 + swz(rr, 32*w + lq*8)) = make_uint2(p0, p1);
  }
  __syncthreads();

  // ---- P4: P = M * A2 (wave owns P row strip r in [16w,16w+16)) ----
  f32x4 acc4[8];
  #pragma unroll
  for (int t=0;t<8;t++) acc4[t] = (f32x4){0.f,0.f,0.f,0.f};
  {
    bf16x8 am[4];                   // A-frag cache: M rows r=16w+lm
    #pragma unroll
    for (int kk=0;kk<4;kk++){
      int rr = 16*w + lm;
      am[kk] = *(const bf16x8*)(B0 + rr*256 + swz(rr, kk*64 + lq*16));
    }
    #pragma unroll
    for (int kk=0;kk<4;kk++){
      #pragma unroll
      for (int ct=0;ct<8;ct++){
        int jr = ct*16 + lm;        // B-frag: A2T row j
        bf16x8 ba2 = *(const bf16x8*)(B2 + jr*256 + swz(jr, kk*64 + lq*16));
        acc4[ct] = __builtin_amdgcn_mfma_f32_16x16x32_bf16(am[kk], ba2, acc4[ct], 0,0,0);
      }
    }
  }
  float* pout = Pf + gbase;
  #pragma unroll
  for (int ct=0;ct<8;ct++){
    #pragma unroll
    for (int r4=0;r4<4;r4++){
      int rr = 16*w + lq*4 + r4;
      pout[rr*HH + ct*16 + lm] = acc4[ct][r4];
    }
  }
}

// ---------------- Kernel 3: out = relu(conv1x1(P, w3, b3)) fp32 -----------
__global__ __launch_bounds__(256) void rc_conv_out(
    const float* __restrict__ Pf, const float* __restrict__ w3,
    const float* __restrict__ b3, float* __restrict__ out)
{
  __shared__ float wT[NCH*NCH];
  __shared__ float bias[NCH];
  const int b  = blockIdx.y;
  const int pt = blockIdx.x;
  const int tid = threadIdx.x;
  for (int i = tid; i < NCH*NCH; i += 256){
    int c = i >> 6, cp = i & 63;
    wT[cp*NCH + c] = w3[i];
  }
  if (tid < NCH) bias[tid] = b3[tid];
  __syncthreads();

  const size_t p0 = (size_t)pt*512 + tid;
  const size_t p1 = p0 + 256;
  const float* s0 = Pf + (size_t)b*NCH*NPOS;

  float acc0[NCH], acc1[NCH];
  #pragma unroll
  for (int c=0;c<NCH;c++){ acc0[c]=0.f; acc1[c]=0.f; }

  #pragma unroll 2
  for (int cp=0; cp<NCH; cp++){
    float xv0 = s0[(size_t)cp*NPOS + p0];
    float xv1 = s0[(size_t)cp*NPOS + p1];
    const float4* wrow = (const float4*)&wT[cp*NCH];
    #pragma unroll
    for (int cg=0; cg<16; cg++){
      float4 wv = wrow[cg];
      acc0[cg*4+0] = fmaf(wv.x, xv0, acc0[cg*4+0]);
      acc0[cg*4+1] = fmaf(wv.y, xv0, acc0[cg*4+1]);
      acc0[cg*4+2] = fmaf(wv.z, xv0, acc0[cg*4+2]);
      acc0[cg*4+3] = fmaf(wv.w, xv0, acc0[cg*4+3]);
      acc1[cg*4+0] = fmaf(wv.x, xv1, acc1[cg*4+0]);
      acc1[cg*4+1] = fmaf(wv.y, xv1, acc1[cg*4+1]);
      acc1[cg*4+2] = fmaf(wv.z, xv1, acc1[cg*4+2]);
      acc1[cg*4+3] = fmaf(wv.w, xv1, acc1[cg*4+3]);
    }
  }
  #pragma unroll
  for (int c=0;c<NCH;c++){
    float v0 = fmaxf(acc0[c]+bias[c], 0.f);
    float v1 = fmaxf(acc1[c]+bias[c], 0.f);
    size_t base = ((size_t)b*NCH + c)*NPOS;
    out[base+p0] = v0;
    out[base+p1] = v1;
  }
}

extern "C" void kernel_launch(void* const* d_in, const int* in_sizes, int n_in,
                              void* d_out, int out_size, void* d_ws, size_t ws_size,
                              hipStream_t stream)
{
  const float* x   = (const float*)d_in[0];
  const float* att = (const float*)d_in[1];
  const float* w0  = (const float*)d_in[2]; const float* b0 = (const float*)d_in[3];
  const float* w1  = (const float*)d_in[4]; const float* b1 = (const float*)d_in[5];
  const float* w2  = (const float*)d_in[6]; const float* b2 = (const float*)d_in[7];
  const float* w3  = (const float*)d_in[8]; const float* b3 = (const float*)d_in[9];

  const size_t NM = (size_t)NB*NCH*NPOS;          // 16,777,216 elems per matrix
  unsigned short* Qb = (unsigned short*)d_ws;     // bf16, 33.55 MB
  unsigned short* Kb = Qb + NM;
  unsigned short* Vb = Kb + NM;
  float* Pf = (float*)((char*)d_ws + 3*NM*sizeof(unsigned short));  // fp32, 67.1 MB
  float* out = (float*)d_out;

  (void)hipFuncSetAttribute((const void*)rc_attention_mfma,
                            hipFuncAttributeMaxDynamicSharedMemorySize, 131072);

  dim3 g1(32, NB, 3);
  rc_conv_qkv<<<g1, 256, 0, stream>>>(x, att, w0,b0, w1,b1, w2,b2, Qb, Kb, Vb);

  rc_attention_mfma<<<dim3(NB*NCH), 512, 131072, stream>>>(Qb, Kb, Vb, Pf);

  dim3 g3(32, NB, 1);
  rc_conv_out<<<g3, 256, 0, stream>>>(Pf, w3, b3, out);
}

// Round 3
// 125.550 us; speedup vs baseline: 7.2319x; 1.9954x over previous
//
#include <hip/hip_runtime.h>
#include <stdint.h>

// Problem: B=16, C=64, H=W=128. fp32 in/out.
#define NB   16
#define NCH  64
#define HH   128
#define NPOS (HH*HH)        // 16384 spatial positions

typedef short bf16x8 __attribute__((ext_vector_type(8)));   // 8 bf16 = 4 VGPRs
typedef float f32x4  __attribute__((ext_vector_type(4)));

__device__ __forceinline__ unsigned short f2bf(float f){
  unsigned int u = __float_as_uint(f);
  u += 0x7FFFu + ((u>>16)&1u);          // RNE; inputs finite
  return (unsigned short)(u>>16);
}
__device__ __forceinline__ unsigned int pk2(float a, float b){
  return (unsigned int)f2bf(a) | ((unsigned int)f2bf(b)<<16);
}

// XOR swizzle on byte bits 4-6: spreads 16 consecutive rows over 8 16B slots
// (2 rows/slot = 2-way = free on b128 frag reads, m136).
__device__ __forceinline__ int swz(int row, int cb){
  return cb ^ (((row & 7) ^ ((row >> 3) & 7)) << 4);
}

// ---------------- Kernel 1: Q/V (m=0, from x) and K (m=1, from att) -------
// MFMA conv1x1+ReLU -> bf16. Block: 256 thr, 256-position tile.
// LDS: Xs[p=256][c=64] bf16 transposed (32KB) + 2x W bf16 (8KB each) + bias.
__global__ __launch_bounds__(256) void rc_conv_in(
    const float* __restrict__ x, const float* __restrict__ att,
    const float* __restrict__ w0, const float* __restrict__ b0,
    const float* __restrict__ w1, const float* __restrict__ b1,
    const float* __restrict__ w2, const float* __restrict__ b2,
    unsigned short* __restrict__ Qb, unsigned short* __restrict__ Kb,
    unsigned short* __restrict__ Vb)
{
  __shared__ char smem[49664];
  char* Xs  = smem;                    // 256 rows x 128B
  char* WsA = smem + 32768;            // 64 rows x 128B
  char* WsB = smem + 40960;
  float* biasA = (float*)(smem + 49152);
  float* biasB = (float*)(smem + 49408);

  const int tid = threadIdx.x;
  const int m  = blockIdx.z;
  const int b  = blockIdx.y;
  const int pblock = blockIdx.x * 256;
  const float* src = m ? att : x;
  const float* wA  = m ? w1 : w0;
  const float* bA  = m ? b1 : b0;

  // ---- stage W(s) as bf16, swizzled rows ----
  {
    int o = tid >> 2, c0 = (tid & 3) * 16;
    const float4* wr = (const float4*)(wA + o*64 + c0);
    float4 f0 = wr[0], f1 = wr[1], f2v = wr[2], f3 = wr[3];
    uint4 pa, pb;
    pa.x = pk2(f0.x,f0.y);  pa.y = pk2(f0.z,f0.w);
    pa.z = pk2(f1.x,f1.y);  pa.w = pk2(f1.z,f1.w);
    pb.x = pk2(f2v.x,f2v.y); pb.y = pk2(f2v.z,f2v.w);
    pb.z = pk2(f3.x,f3.y);  pb.w = pk2(f3.z,f3.w);
    *(uint4*)(WsA + o*128 + swz(o, c0*2))      = pa;
    *(uint4*)(WsA + o*128 + swz(o, c0*2 + 16)) = pb;
    if (m == 0){
      const float4* wr2 = (const float4*)(w2 + o*64 + c0);
      float4 g0 = wr2[0], g1 = wr2[1], g2 = wr2[2], g3 = wr2[3];
      uint4 qa, qb;
      qa.x = pk2(g0.x,g0.y); qa.y = pk2(g0.z,g0.w);
      qa.z = pk2(g1.x,g1.y); qa.w = pk2(g1.z,g1.w);
      qb.x = pk2(g2.x,g2.y); qb.y = pk2(g2.z,g2.w);
      qb.z = pk2(g3.x,g3.y); qb.w = pk2(g3.z,g3.w);
      *(uint4*)(WsB + o*128 + swz(o, c0*2))      = qa;
      *(uint4*)(WsB + o*128 + swz(o, c0*2 + 16)) = qb;
    }
  }
  if (tid < 64){
    biasA[tid] = bA[tid];
    if (m == 0) biasB[tid] = b2[tid];
  }

  // ---- stage X tile transposed: Xs[p][c], 4-channel-packed b64 writes ----
  const float* S = src + (size_t)b*NCH*NPOS + pblock;
  #pragma unroll
  for (int it=0; it<4; ++it){
    int unit = tid + 256*it;          // 0..1023 = 16 cquads x 64 pgroups
    int q  = unit >> 6;               // channel quad 0..15
    int p4 = (unit & 63) << 2;        // position 0..255 step 4
    float4 r0 = *(const float4*)(S + (size_t)(4*q+0)*NPOS + p4);
    float4 r1 = *(const float4*)(S + (size_t)(4*q+1)*NPOS + p4);
    float4 r2 = *(const float4*)(S + (size_t)(4*q+2)*NPOS + p4);
    float4 r3 = *(const float4*)(S + (size_t)(4*q+3)*NPOS + p4);
    const float* c0 = (const float*)&r0;
    const float* c1 = (const float*)&r1;
    const float* c2 = (const float*)&r2;
    const float* c3 = (const float*)&r3;
    #pragma unroll
    for (int u=0; u<4; ++u){
      uint2 pk;
      pk.x = pk2(c0[u], c1[u]);
      pk.y = pk2(c2[u], c3[u]);
      *(uint2*)(Xs + (p4+u)*128 + swz(p4+u, q*8)) = pk;
    }
  }
  __syncthreads();

  // ---- MFMA: D[o',p'] = sum_c W[o,c]*X[p,c]; o'=4lq+r4 rows, p'=lm cols ----
  const int w = tid>>6, l = tid&63, lq = l>>4, lm = l&15;
  bf16x8 aQ[2], aV[2] = {};
  {
    int orow = 16*w + lm;
    aQ[0] = *(const bf16x8*)(WsA + orow*128 + swz(orow,      lq*16));
    aQ[1] = *(const bf16x8*)(WsA + orow*128 + swz(orow, 64 + lq*16));
    if (m == 0){
      aV[0] = *(const bf16x8*)(WsB + orow*128 + swz(orow,      lq*16));
      aV[1] = *(const bf16x8*)(WsB + orow*128 + swz(orow, 64 + lq*16));
    }
  }
  float bQv[4], bVv[4];
  #pragma unroll
  for (int r4=0;r4<4;r4++){
    int o = 16*w + 4*lq + r4;
    bQv[r4] = biasA[o];
    bVv[r4] = (m==0) ? biasB[o] : 0.f;
  }
  unsigned short* dA = (m ? Kb : Qb) + (size_t)b*NCH*NPOS;
  unsigned short* dB = Vb + (size_t)b*NCH*NPOS;

  #pragma unroll
  for (int pt=0; pt<16; ++pt){
    int prow = pt*16 + lm;
    bf16x8 bx0 = *(const bf16x8*)(Xs + prow*128 + swz(prow,      lq*16));
    bf16x8 bx1 = *(const bf16x8*)(Xs + prow*128 + swz(prow, 64 + lq*16));
    f32x4 accQ = (f32x4){0.f,0.f,0.f,0.f};
    accQ = __builtin_amdgcn_mfma_f32_16x16x32_bf16(aQ[0], bx0, accQ, 0,0,0);
    accQ = __builtin_amdgcn_mfma_f32_16x16x32_bf16(aQ[1], bx1, accQ, 0,0,0);
    int p = pblock + pt*16 + lm;
    #pragma unroll
    for (int r4=0;r4<4;r4++){
      int o = 16*w + 4*lq + r4;
      dA[(size_t)o*NPOS + p] = f2bf(fmaxf(accQ[r4] + bQv[r4], 0.f));
    }
    if (m == 0){
      f32x4 accV = (f32x4){0.f,0.f,0.f,0.f};
      accV = __builtin_amdgcn_mfma_f32_16x16x32_bf16(aV[0], bx0, accV, 0,0,0);
      accV = __builtin_amdgcn_mfma_f32_16x16x32_bf16(aV[1], bx1, accV, 0,0,0);
      #pragma unroll
      for (int r4=0;r4<4;r4++){
        int o = 16*w + 4*lq + r4;
        dB[(size_t)o*NPOS + p] = f2bf(fmaxf(accV[r4] + bVv[r4], 0.f));
      }
    }
  }
}

// ---------------- Kernel 2: fused per-(b,c) MFMA attention ----------------
// 1024 blocks x 512 threads (8 waves). LDS = 4 x 32KB swizzled buffers.
__global__ __launch_bounds__(512) void rc_attention_mfma(
    const unsigned short* __restrict__ Qb, const unsigned short* __restrict__ Kb,
    const unsigned short* __restrict__ Vb, unsigned short* __restrict__ Pb)
{
  extern __shared__ char lds[];
  char* B0 = lds;
  char* B1 = lds + 32768;
  char* B2 = lds + 65536;
  char* B3 = lds + 98304;
  const int tid = threadIdx.x;
  const int l  = tid & 63;
  const int w  = tid >> 6;          // wave 0..7
  const int lq = l >> 4;            // quarter 0..3
  const int lm = l & 15;
  const size_t gbase = (size_t)blockIdx.x * NPOS;

  // ---- V global loads early (held in regs through P1/P2) ----
  uint4 vreg[4];
  #pragma unroll
  for (int i=0;i<4;i++)
    vreg[i] = *(const uint4*)(Vb + gbase + (size_t)(tid + 512*i)*8);

  // ---- stage Q,K row-major + transposed ----
  #pragma unroll
  for (int i=0;i<4;i++){
    int e = (tid + 512*i)*8;
    int row = e >> 7, col = e & 127;
    uint4 q = *(const uint4*)(Qb + gbase + e);
    uint4 k = *(const uint4*)(Kb + gbase + e);
    *(uint4*)(B0 + row*256 + swz(row, col*2)) = q;
    *(uint4*)(B1 + row*256 + swz(row, col*2)) = k;
    unsigned int qd[4] = {q.x,q.y,q.z,q.w};
    unsigned int kd[4] = {k.x,k.y,k.z,k.w};
    #pragma unroll
    for (int u=0;u<8;u++){
      unsigned short qe = (unsigned short)(qd[u>>1] >> (16*(u&1)));
      unsigned short ke = (unsigned short)(kd[u>>1] >> (16*(u&1)));
      int tr = col + u;             // T-row = original col
      *(unsigned short*)(B2 + tr*256 + swz(tr, row*2)) = qe;
      *(unsigned short*)(B3 + tr*256 + swz(tr, row*2)) = ke;
    }
  }
  __syncthreads();

  // ---- P1: S1T = K * Q^T ----
  f32x4 acc1[8];
  #pragma unroll
  for (int t=0;t<8;t++) acc1[t] = (f32x4){0.f,0.f,0.f,0.f};
  {
    bf16x8 bq[4];
    #pragma unroll
    for (int kk=0;kk<4;kk++){
      int r = 16*w + lm;
      bq[kk] = *(const bf16x8*)(B0 + r*256 + swz(r, kk*64 + lq*16));
    }
    #pragma unroll
    for (int kk=0;kk<4;kk++){
      #pragma unroll
      for (int jt=0;jt<8;jt++){
        int jr = jt*16 + lm;
        bf16x8 ak = *(const bf16x8*)(B1 + jr*256 + swz(jr, kk*64 + lq*16));
        acc1[jt] = __builtin_amdgcn_mfma_f32_16x16x32_bf16(ak, bq[kk], acc1[jt], 0,0,0);
      }
    }
  }
  unsigned int a1p[8][2];
  {
    float mx = -1e30f;
    #pragma unroll
    for (int t=0;t<8;t++)
      mx = fmaxf(mx, fmaxf(fmaxf(acc1[t][0], acc1[t][1]), fmaxf(acc1[t][2], acc1[t][3])));
    mx = fmaxf(mx, __shfl_xor(mx, 16));
    mx = fmaxf(mx, __shfl_xor(mx, 32));
    float sum = 0.f;
    #pragma unroll
    for (int t=0;t<8;t++){
      #pragma unroll
      for (int r4=0;r4<4;r4++){ float e = __expf(acc1[t][r4] - mx); acc1[t][r4] = e; sum += e; }
    }
    sum += __shfl_xor(sum, 16);
    sum += __shfl_xor(sum, 32);
    float inv = 1.f/sum;
    #pragma unroll
    for (int t=0;t<8;t++){
      a1p[t][0] = pk2(acc1[t][0]*inv, acc1[t][1]*inv);
      a1p[t][1] = pk2(acc1[t][2]*inv, acc1[t][3]*inv);
    }
  }

  // ---- P2: S2 = K^T * Q ----
  f32x4 acc2[8];
  #pragma unroll
  for (int t=0;t<8;t++) acc2[t] = (f32x4){0.f,0.f,0.f,0.f};
  {
    bf16x8 akt[4];
    #pragma unroll
    for (int kk=0;kk<4;kk++){
      int ir = 16*w + lm;
      akt[kk] = *(const bf16x8*)(B3 + ir*256 + swz(ir, kk*64 + lq*16));
    }
    #pragma unroll
    for (int kk=0;kk<4;kk++){
      #pragma unroll
      for (int ct=0;ct<8;ct++){
        int jr = ct*16 + lm;
        bf16x8 bqt = *(const bf16x8*)(B2 + jr*256 + swz(jr, kk*64 + lq*16));
        acc2[ct] = __builtin_amdgcn_mfma_f32_16x16x32_bf16(akt[kk], bqt, acc2[ct], 0,0,0);
      }
    }
  }
  unsigned int a2p[8][2];
  {
    float m0=-1e30f, m1=-1e30f, m2=-1e30f, m3=-1e30f;
    #pragma unroll
    for (int t=0;t<8;t++){
      m0 = fmaxf(m0, acc2[t][0]); m1 = fmaxf(m1, acc2[t][1]);
      m2 = fmaxf(m2, acc2[t][2]); m3 = fmaxf(m3, acc2[t][3]);
    }
    #pragma unroll
    for (int d=1; d<16; d<<=1){
      m0 = fmaxf(m0, __shfl_xor(m0,d)); m1 = fmaxf(m1, __shfl_xor(m1,d));
      m2 = fmaxf(m2, __shfl_xor(m2,d)); m3 = fmaxf(m3, __shfl_xor(m3,d));
    }
    float s0=0.f, s1=0.f, s2=0.f, s3=0.f;
    #pragma unroll
    for (int t=0;t<8;t++){
      float e0 = __expf(acc2[t][0]-m0); acc2[t][0]=e0; s0 += e0;
      float e1 = __expf(acc2[t][1]-m1); acc2[t][1]=e1; s1 += e1;
      float e2 = __expf(acc2[t][2]-m2); acc2[t][2]=e2; s2 += e2;
      float e3 = __expf(acc2[t][3]-m3); acc2[t][3]=e3; s3 += e3;
    }
    #pragma unroll
    for (int d=1; d<16; d<<=1){
      s0 += __shfl_xor(s0,d); s1 += __shfl_xor(s1,d);
      s2 += __shfl_xor(s2,d); s3 += __shfl_xor(s3,d);
    }
    float i0=1.f/s0, i1=1.f/s1, i2=1.f/s2, i3=1.f/s3;
    #pragma unroll
    for (int t=0;t<8;t++){
      a2p[t][0] = pk2(acc2[t][0]*i0, acc2[t][1]*i1);
      a2p[t][1] = pk2(acc2[t][2]*i2, acc2[t][3]*i3);
    }
  }

  __syncthreads();

  // ---- write A1 -> B3 (rm), A2T -> B2 (rm), VT -> B1 ----
  {
    int r = 16*w + lm;
    #pragma unroll
    for (int t=0;t<8;t++)
      *(uint2*)(B3 + r*256 + swz(r, t*32 + lq*8)) = make_uint2(a1p[t][0], a1p[t][1]);
  }
  #pragma unroll
  for (int t=0;t<8;t++){
    int jr = t*16 + lm;
    *(uint2*)(B2 + jr*256 + swz(jr, 32*w + lq*8)) = make_uint2(a2p[t][0], a2p[t][1]);
  }
  #pragma unroll
  for (int i=0;i<4;i++){
    int e = (tid + 512*i)*8;
    int row = e>>7, col = e&127;
    unsigned int vd[4] = {vreg[i].x, vreg[i].y, vreg[i].z, vreg[i].w};
    #pragma unroll
    for (int u=0;u<8;u++){
      unsigned short ve = (unsigned short)(vd[u>>1] >> (16*(u&1)));
      int tr = col + u;
      *(unsigned short*)(B1 + tr*256 + swz(tr, row*2)) = ve;
    }
  }
  __syncthreads();

  // ---- P3: MT = V^T * A1^T ----
  f32x4 acc3[8];
  #pragma unroll
  for (int t=0;t<8;t++) acc3[t] = (f32x4){0.f,0.f,0.f,0.f};
  {
    bf16x8 av[4];
    #pragma unroll
    for (int kk=0;kk<4;kk++){
      int jr = 16*w + lm;
      av[kk] = *(const bf16x8*)(B1 + jr*256 + swz(jr, kk*64 + lq*16));
    }
    #pragma unroll
    for (int kk=0;kk<4;kk++){
      #pragma unroll
      for (int rt=0;rt<8;rt++){
        int rr = rt*16 + lm;
        bf16x8 ba = *(const bf16x8*)(B3 + rr*256 + swz(rr, kk*64 + lq*16));
        acc3[rt] = __builtin_amdgcn_mfma_f32_16x16x32_bf16(av[kk], ba, acc3[rt], 0,0,0);
      }
    }
  }
  #pragma unroll
  for (int rt=0;rt<8;rt++){
    int rr = rt*16 + lm;
    unsigned int p0 = pk2(acc3[rt][0], acc3[rt][1]);
    unsigned int p1 = pk2(acc3[rt][2], acc3[rt][3]);
    *(uint2*)(B0 + rr*256 + swz(rr, 32*w + lq*8)) = make_uint2(p0, p1);
  }
  __syncthreads();

  // ---- P4: P = M * A2 -> global bf16 ----
  f32x4 acc4[8];
  #pragma unroll
  for (int t=0;t<8;t++) acc4[t] = (f32x4){0.f,0.f,0.f,0.f};
  {
    bf16x8 am[4];
    #pragma unroll
    for (int kk=0;kk<4;kk++){
      int rr = 16*w + lm;
      am[kk] = *(const bf16x8*)(B0 + rr*256 + swz(rr, kk*64 + lq*16));
    }
    #pragma unroll
    for (int kk=0;kk<4;kk++){
      #pragma unroll
      for (int ct=0;ct<8;ct++){
        int jr = ct*16 + lm;
        bf16x8 ba2 = *(const bf16x8*)(B2 + jr*256 + swz(jr, kk*64 + lq*16));
        acc4[ct] = __builtin_amdgcn_mfma_f32_16x16x32_bf16(am[kk], ba2, acc4[ct], 0,0,0);
      }
    }
  }
  unsigned short* pout = Pb + gbase;
  #pragma unroll
  for (int ct=0;ct<8;ct++){
    #pragma unroll
    for (int r4=0;r4<4;r4++){
      int rr = 16*w + lq*4 + r4;
      pout[rr*HH + ct*16 + lm] = f2bf(acc4[ct][r4]);
    }
  }
}

// ---------------- Kernel 3: out = relu(conv1x1(P, w3, b3)) fp32, MFMA -----
__global__ __launch_bounds__(256) void rc_conv_out(
    const unsigned short* __restrict__ Pb, const float* __restrict__ w3,
    const float* __restrict__ b3, float* __restrict__ out)
{
  __shared__ char smem[41216];
  char* Xs = smem;                     // 256 rows x 128B
  char* Ws = smem + 32768;             // 64 rows x 128B
  float* bias = (float*)(smem + 40960);

  const int tid = threadIdx.x;
  const int b  = blockIdx.y;
  const int pblock = blockIdx.x * 256;

  {
    int o = tid >> 2, c0 = (tid & 3) * 16;
    const float4* wr = (const float4*)(w3 + o*64 + c0);
    float4 f0 = wr[0], f1 = wr[1], f2v = wr[2], f3 = wr[3];
    uint4 pa, pb;
    pa.x = pk2(f0.x,f0.y);  pa.y = pk2(f0.z,f0.w);
    pa.z = pk2(f1.x,f1.y);  pa.w = pk2(f1.z,f1.w);
    pb.x = pk2(f2v.x,f2v.y); pb.y = pk2(f2v.z,f2v.w);
    pb.z = pk2(f3.x,f3.y);  pb.w = pk2(f3.z,f3.w);
    *(uint4*)(Ws + o*128 + swz(o, c0*2))      = pa;
    *(uint4*)(Ws + o*128 + swz(o, c0*2 + 16)) = pb;
  }
  if (tid < 64) bias[tid] = b3[tid];

  const unsigned short* S = Pb + (size_t)b*NCH*NPOS + pblock;
  #pragma unroll
  for (int it=0; it<4; ++it){
    int unit = tid + 256*it;
    int q  = unit >> 6;
    int p4 = (unit & 63) << 2;
    uint2 r0 = *(const uint2*)(S + (size_t)(4*q+0)*NPOS + p4);
    uint2 r1 = *(const uint2*)(S + (size_t)(4*q+1)*NPOS + p4);
    uint2 r2 = *(const uint2*)(S + (size_t)(4*q+2)*NPOS + p4);
    uint2 r3 = *(const uint2*)(S + (size_t)(4*q+3)*NPOS + p4);
    const unsigned short* u0 = (const unsigned short*)&r0;
    const unsigned short* u1 = (const unsigned short*)&r1;
    const unsigned short* u2 = (const unsigned short*)&r2;
    const unsigned short* u3 = (const unsigned short*)&r3;
    #pragma unroll
    for (int u=0; u<4; ++u){
      uint2 pk;
      pk.x = (unsigned int)u0[u] | ((unsigned int)u1[u]<<16);
      pk.y = (unsigned int)u2[u] | ((unsigned int)u3[u]<<16);
      *(uint2*)(Xs + (p4+u)*128 + swz(p4+u, q*8)) = pk;
    }
  }
  __syncthreads();

  const int w = tid>>6, l = tid&63, lq = l>>4, lm = l&15;
  bf16x8 aW[2];
  {
    int orow = 16*w + lm;
    aW[0] = *(const bf16x8*)(Ws + orow*128 + swz(orow,      lq*16));
    aW[1] = *(const bf16x8*)(Ws + orow*128 + swz(orow, 64 + lq*16));
  }
  float bv[4];
  #pragma unroll
  for (int r4=0;r4<4;r4++) bv[r4] = bias[16*w + 4*lq + r4];

  float* dst = out + (size_t)b*NCH*NPOS;
  #pragma unroll
  for (int pt=0; pt<16; ++pt){
    int prow = pt*16 + lm;
    bf16x8 bx0 = *(const bf16x8*)(Xs + prow*128 + swz(prow,      lq*16));
    bf16x8 bx1 = *(const bf16x8*)(Xs + prow*128 + swz(prow, 64 + lq*16));
    f32x4 acc = (f32x4){0.f,0.f,0.f,0.f};
    acc = __builtin_amdgcn_mfma_f32_16x16x32_bf16(aW[0], bx0, acc, 0,0,0);
    acc = __builtin_amdgcn_mfma_f32_16x16x32_bf16(aW[1], bx1, acc, 0,0,0);
    int p = pblock + pt*16 + lm;
    #pragma unroll
    for (int r4=0;r4<4;r4++){
      int o = 16*w + 4*lq + r4;
      dst[(size_t)o*NPOS + p] = fmaxf(acc[r4] + bv[r4], 0.f);
    }
  }
}

extern "C" void kernel_launch(void* const* d_in, const int* in_sizes, int n_in,
                              void* d_out, int out_size, void* d_ws, size_t ws_size,
                              hipStream_t stream)
{
  const float* x   = (const float*)d_in[0];
  const float* att = (const float*)d_in[1];
  const float* w0  = (const float*)d_in[2]; const float* b0 = (const float*)d_in[3];
  const float* w1  = (const float*)d_in[4]; const float* b1 = (const float*)d_in[5];
  const float* w2  = (const float*)d_in[6]; const float* b2 = (const float*)d_in[7];
  const float* w3  = (const float*)d_in[8]; const float* b3 = (const float*)d_in[9];

  const size_t NM = (size_t)NB*NCH*NPOS;          // 16,777,216 elems per matrix
  unsigned short* Qb = (unsigned short*)d_ws;     // bf16, 33.55 MB each
  unsigned short* Kb = Qb + NM;
  unsigned short* Vb = Kb + NM;
  unsigned short* Pb = Vb + NM;
  float* out = (float*)d_out;

  (void)hipFuncSetAttribute((const void*)rc_attention_mfma,
                            hipFuncAttributeMaxDynamicSharedMemorySize, 131072);

  rc_conv_in<<<dim3(64, NB, 2), 256, 0, stream>>>(x, att, w0,b0, w1,b1, w2,b2,
                                                  Qb, Kb, Vb);

  rc_attention_mfma<<<dim3(NB*NCH), 512, 131072, stream>>>(Qb, Kb, Vb, Pb);

  rc_conv_out<<<dim3(64, NB), 256, 0, stream>>>(Pb, w3, b3, out);
}

// Round 4
// 118.885 us; speedup vs baseline: 7.6374x; 1.0561x over previous
//
#include <hip/hip_runtime.h>
#include <stdint.h>

// Problem: B=16, C=64, H=W=128. fp32 in/out.
#define NB   16
#define NCH  64
#define HH   128
#define NPOS (HH*HH)        // 16384 spatial positions

typedef short bf16x8 __attribute__((ext_vector_type(8)));   // 8 bf16 = 4 VGPRs
typedef float f32x4  __attribute__((ext_vector_type(4)));

__device__ __forceinline__ unsigned short f2bf(float f){
  unsigned int u = __float_as_uint(f);
  u += 0x7FFFu + ((u>>16)&1u);          // RNE; inputs finite
  return (unsigned short)(u>>16);
}
__device__ __forceinline__ unsigned int pk2(float a, float b){
  return (unsigned int)f2bf(a) | ((unsigned int)f2bf(b)<<16);
}

// XOR swizzle on byte bits 4-6: spreads 16 consecutive rows over 8 16B slots
// (2 rows/slot = 2-way = free on b128 frag reads, m136).
__device__ __forceinline__ int swz(int row, int cb){
  return cb ^ (((row & 7) ^ ((row >> 3) & 7)) << 4);
}

// ---------------- Kernel 1: Q/V (m=0, from x) and K (m=1, from att) -------
// MFMA conv1x1+ReLU -> bf16. Block: 256 thr, 128-position tile.
// LDS: Xs[p=128][c=64] bf16 (16KB) + WsA/WsB (8KB each) + bias = 33.25KB
// -> 4 blocks/CU. All 8 staging loads in flight before LDS writes.
// Output via LDS bounce -> 64B-aligned uint4 stores (no write amplification).
__global__ __launch_bounds__(256, 4) void rc_conv_in(
    const float* __restrict__ x, const float* __restrict__ att,
    const float* __restrict__ w0, const float* __restrict__ b0,
    const float* __restrict__ w1, const float* __restrict__ b1,
    const float* __restrict__ w2, const float* __restrict__ b2,
    unsigned short* __restrict__ Qb, unsigned short* __restrict__ Kb,
    unsigned short* __restrict__ Vb)
{
  __shared__ char smem[33280];
  char* Xs  = smem;                    // 128 p-rows x 128 B  (later: out bounce 64 o-rows x 256 B)
  char* WsA = smem + 16384;            // 64 o-rows x 128 B
  char* WsB = smem + 24576;
  float* biasA = (float*)(smem + 32768);
  float* biasB = (float*)(smem + 33024);

  const int tid = threadIdx.x;
  const int m  = blockIdx.z;
  const int b  = blockIdx.y;
  const int pblock = blockIdx.x * 128;
  const float* src = m ? att : x;
  const float* wA  = m ? w1 : w0;
  const float* bA  = m ? b1 : b0;

  // ---- stage W(s) as bf16, swizzled rows ----
  {
    int o = tid >> 2, c0 = (tid & 3) * 16;
    const float4* wr = (const float4*)(wA + o*64 + c0);
    float4 f0 = wr[0], f1 = wr[1], f2v = wr[2], f3 = wr[3];
    uint4 pa, pb;
    pa.x = pk2(f0.x,f0.y);  pa.y = pk2(f0.z,f0.w);
    pa.z = pk2(f1.x,f1.y);  pa.w = pk2(f1.z,f1.w);
    pb.x = pk2(f2v.x,f2v.y); pb.y = pk2(f2v.z,f2v.w);
    pb.z = pk2(f3.x,f3.y);  pb.w = pk2(f3.z,f3.w);
    *(uint4*)(WsA + o*128 + swz(o, c0*2))      = pa;
    *(uint4*)(WsA + o*128 + swz(o, c0*2 + 16)) = pb;
    if (m == 0){
      const float4* wr2 = (const float4*)(w2 + o*64 + c0);
      float4 g0 = wr2[0], g1 = wr2[1], g2 = wr2[2], g3 = wr2[3];
      uint4 qa, qb;
      qa.x = pk2(g0.x,g0.y); qa.y = pk2(g0.z,g0.w);
      qa.z = pk2(g1.x,g1.y); qa.w = pk2(g1.z,g1.w);
      qb.x = pk2(g2.x,g2.y); qb.y = pk2(g2.z,g2.w);
      qb.z = pk2(g3.x,g3.y); qb.w = pk2(g3.z,g3.w);
      *(uint4*)(WsB + o*128 + swz(o, c0*2))      = qa;
      *(uint4*)(WsB + o*128 + swz(o, c0*2 + 16)) = qb;
    }
  }
  if (tid < 64){
    biasA[tid] = bA[tid];
    if (m == 0) biasB[tid] = b2[tid];
  }

  // ---- stage X tile: ALL 8 loads issued, then transpose-pack to LDS ----
  const float* S = src + (size_t)b*NCH*NPOS + pblock;
  float4 xr[2][4];
  #pragma unroll
  for (int g=0; g<2; ++g){
    int unit = tid + 256*g;           // 0..511 = 16 cquads x 32 pgroups
    int q  = unit >> 5;               // channel quad 0..15
    int p4 = (unit & 31) << 2;        // position 0..127 step 4
    #pragma unroll
    for (int j=0;j<4;j++)
      xr[g][j] = *(const float4*)(S + (size_t)(4*q+j)*NPOS + p4);
  }
  #pragma unroll
  for (int g=0; g<2; ++g){
    int unit = tid + 256*g;
    int q  = unit >> 5;
    int p4 = (unit & 31) << 2;
    const float* c0 = (const float*)&xr[g][0];
    const float* c1 = (const float*)&xr[g][1];
    const float* c2 = (const float*)&xr[g][2];
    const float* c3 = (const float*)&xr[g][3];
    #pragma unroll
    for (int u=0; u<4; ++u){
      uint2 pk;
      pk.x = pk2(c0[u], c1[u]);
      pk.y = pk2(c2[u], c3[u]);
      *(uint2*)(Xs + (p4+u)*128 + swz(p4+u, q*8)) = pk;
    }
  }
  __syncthreads();

  // ---- MFMA: D[o',p'] = sum_c W[o,c]*X[p,c] ----
  const int w = tid>>6, l = tid&63, lq = l>>4, lm = l&15;
  bf16x8 aQ[2], aV[2] = {};
  {
    int orow = 16*w + lm;
    aQ[0] = *(const bf16x8*)(WsA + orow*128 + swz(orow,      lq*16));
    aQ[1] = *(const bf16x8*)(WsA + orow*128 + swz(orow, 64 + lq*16));
    if (m == 0){
      aV[0] = *(const bf16x8*)(WsB + orow*128 + swz(orow,      lq*16));
      aV[1] = *(const bf16x8*)(WsB + orow*128 + swz(orow, 64 + lq*16));
    }
  }
  float bQv[4], bVv[4];
  #pragma unroll
  for (int r4=0;r4<4;r4++){
    int o = 16*w + 4*lq + r4;
    bQv[r4] = biasA[o];
    bVv[r4] = (m==0) ? biasB[o] : 0.f;
  }

  f32x4 accQ[8], accV[8];
  #pragma unroll
  for (int pt=0;pt<8;pt++){ accQ[pt]=(f32x4){0,0,0,0}; accV[pt]=(f32x4){0,0,0,0}; }
  #pragma unroll
  for (int pt=0; pt<8; ++pt){
    int prow = pt*16 + lm;
    bf16x8 bx0 = *(const bf16x8*)(Xs + prow*128 + swz(prow,      lq*16));
    bf16x8 bx1 = *(const bf16x8*)(Xs + prow*128 + swz(prow, 64 + lq*16));
    accQ[pt] = __builtin_amdgcn_mfma_f32_16x16x32_bf16(aQ[0], bx0, accQ[pt], 0,0,0);
    accQ[pt] = __builtin_amdgcn_mfma_f32_16x16x32_bf16(aQ[1], bx1, accQ[pt], 0,0,0);
    if (m == 0){
      accV[pt] = __builtin_amdgcn_mfma_f32_16x16x32_bf16(aV[0], bx0, accV[pt], 0,0,0);
      accV[pt] = __builtin_amdgcn_mfma_f32_16x16x32_bf16(aV[1], bx1, accV[pt], 0,0,0);
    }
  }

  // ---- bounce + coalesced store. Xs reused as 64 o-rows x 256 B,
  //      per-row byte skew 32*((o>>2)&7) -> conflict-free quarter octets. ----
  unsigned short* dA = (m ? Kb : Qb) + (size_t)b*NCH*NPOS;
  unsigned short* dB = Vb + (size_t)b*NCH*NPOS;
  const int skw = 32*((4*w + lq) & 7);     // = 32*((o>>2)&7) for this quarter

  __syncthreads();                          // all MFMA frag reads of Xs done
  #pragma unroll
  for (int pt=0; pt<8; ++pt){
    #pragma unroll
    for (int r4=0;r4<4;r4++){
      int o = 16*w + 4*lq + r4;
      int p = pt*16 + lm;
      *(unsigned short*)(Xs + o*256 + ((2*p + skw) & 255)) =
          f2bf(fmaxf(accQ[pt][r4] + bQv[r4], 0.f));
    }
  }
  __syncthreads();
  {
    int o = tid >> 2, jj = tid & 3;
    int sk2 = 32*((o>>2)&7);
    #pragma unroll
    for (int i=0;i<4;i++){
      int j = i*4 + jj;                    // 16B chunk index in row
      uint4 v = *(const uint4*)(Xs + o*256 + ((j*16 + sk2) & 255));
      *(uint4*)(dA + (size_t)o*NPOS + pblock + j*8) = v;
    }
  }
  if (m == 0){
    __syncthreads();                        // store-reads done before overwrite
    #pragma unroll
    for (int pt=0; pt<8; ++pt){
      #pragma unroll
      for (int r4=0;r4<4;r4++){
        int o = 16*w + 4*lq + r4;
        int p = pt*16 + lm;
        *(unsigned short*)(Xs + o*256 + ((2*p + skw) & 255)) =
            f2bf(fmaxf(accV[pt][r4] + bVv[r4], 0.f));
      }
    }
    __syncthreads();
    int o = tid >> 2, jj = tid & 3;
    int sk2 = 32*((o>>2)&7);
    #pragma unroll
    for (int i=0;i<4;i++){
      int j = i*4 + jj;
      uint4 v = *(const uint4*)(Xs + o*256 + ((j*16 + sk2) & 255));
      *(uint4*)(dB + (size_t)o*NPOS + pblock + j*8) = v;
    }
  }
}

// ---------------- Kernel 2: fused per-(b,c) MFMA attention ----------------
// 1024 blocks x 512 threads (8 waves). LDS = 4 x 32KB swizzled buffers.
__global__ __launch_bounds__(512) void rc_attention_mfma(
    const unsigned short* __restrict__ Qb, const unsigned short* __restrict__ Kb,
    const unsigned short* __restrict__ Vb, unsigned short* __restrict__ Pb)
{
  extern __shared__ char lds[];
  char* B0 = lds;
  char* B1 = lds + 32768;
  char* B2 = lds + 65536;
  char* B3 = lds + 98304;
  const int tid = threadIdx.x;
  const int l  = tid & 63;
  const int w  = tid >> 6;          // wave 0..7
  const int lq = l >> 4;            // quarter 0..3
  const int lm = l & 15;
  const size_t gbase = (size_t)blockIdx.x * NPOS;

  // ---- V global loads early (held in regs through P1/P2) ----
  uint4 vreg[4];
  #pragma unroll
  for (int i=0;i<4;i++)
    vreg[i] = *(const uint4*)(Vb + gbase + (size_t)(tid + 512*i)*8);

  // ---- stage Q,K row-major + transposed ----
  #pragma unroll
  for (int i=0;i<4;i++){
    int e = (tid + 512*i)*8;
    int row = e >> 7, col = e & 127;
    uint4 q = *(const uint4*)(Qb + gbase + e);
    uint4 k = *(const uint4*)(Kb + gbase + e);
    *(uint4*)(B0 + row*256 + swz(row, col*2)) = q;
    *(uint4*)(B1 + row*256 + swz(row, col*2)) = k;
    unsigned int qd[4] = {q.x,q.y,q.z,q.w};
    unsigned int kd[4] = {k.x,k.y,k.z,k.w};
    #pragma unroll
    for (int u=0;u<8;u++){
      unsigned short qe = (unsigned short)(qd[u>>1] >> (16*(u&1)));
      unsigned short ke = (unsigned short)(kd[u>>1] >> (16*(u&1)));
      int tr = col + u;             // T-row = original col
      *(unsigned short*)(B2 + tr*256 + swz(tr, row*2)) = qe;
      *(unsigned short*)(B3 + tr*256 + swz(tr, row*2)) = ke;
    }
  }
  __syncthreads();

  // ---- P1: S1T = K * Q^T ----
  f32x4 acc1[8];
  #pragma unroll
  for (int t=0;t<8;t++) acc1[t] = (f32x4){0.f,0.f,0.f,0.f};
  {
    bf16x8 bq[4];
    #pragma unroll
    for (int kk=0;kk<4;kk++){
      int r = 16*w + lm;
      bq[kk] = *(const bf16x8*)(B0 + r*256 + swz(r, kk*64 + lq*16));
    }
    #pragma unroll
    for (int kk=0;kk<4;kk++){
      #pragma unroll
      for (int jt=0;jt<8;jt++){
        int jr = jt*16 + lm;
        bf16x8 ak = *(const bf16x8*)(B1 + jr*256 + swz(jr, kk*64 + lq*16));
        acc1[jt] = __builtin_amdgcn_mfma_f32_16x16x32_bf16(ak, bq[kk], acc1[jt], 0,0,0);
      }
    }
  }
  unsigned int a1p[8][2];
  {
    float mx = -1e30f;
    #pragma unroll
    for (int t=0;t<8;t++)
      mx = fmaxf(mx, fmaxf(fmaxf(acc1[t][0], acc1[t][1]), fmaxf(acc1[t][2], acc1[t][3])));
    mx = fmaxf(mx, __shfl_xor(mx, 16));
    mx = fmaxf(mx, __shfl_xor(mx, 32));
    float sum = 0.f;
    #pragma unroll
    for (int t=0;t<8;t++){
      #pragma unroll
      for (int r4=0;r4<4;r4++){ float e = __expf(acc1[t][r4] - mx); acc1[t][r4] = e; sum += e; }
    }
    sum += __shfl_xor(sum, 16);
    sum += __shfl_xor(sum, 32);
    float inv = 1.f/sum;
    #pragma unroll
    for (int t=0;t<8;t++){
      a1p[t][0] = pk2(acc1[t][0]*inv, acc1[t][1]*inv);
      a1p[t][1] = pk2(acc1[t][2]*inv, acc1[t][3]*inv);
    }
  }

  // ---- P2: S2 = K^T * Q ----
  f32x4 acc2[8];
  #pragma unroll
  for (int t=0;t<8;t++) acc2[t] = (f32x4){0.f,0.f,0.f,0.f};
  {
    bf16x8 akt[4];
    #pragma unroll
    for (int kk=0;kk<4;kk++){
      int ir = 16*w + lm;
      akt[kk] = *(const bf16x8*)(B3 + ir*256 + swz(ir, kk*64 + lq*16));
    }
    #pragma unroll
    for (int kk=0;kk<4;kk++){
      #pragma unroll
      for (int ct=0;ct<8;ct++){
        int jr = ct*16 + lm;
        bf16x8 bqt = *(const bf16x8*)(B2 + jr*256 + swz(jr, kk*64 + lq*16));
        acc2[ct] = __builtin_amdgcn_mfma_f32_16x16x32_bf16(akt[kk], bqt, acc2[ct], 0,0,0);
      }
    }
  }
  unsigned int a2p[8][2];
  {
    float m0=-1e30f, m1=-1e30f, m2=-1e30f, m3=-1e30f;
    #pragma unroll
    for (int t=0;t<8;t++){
      m0 = fmaxf(m0, acc2[t][0]); m1 = fmaxf(m1, acc2[t][1]);
      m2 = fmaxf(m2, acc2[t][2]); m3 = fmaxf(m3, acc2[t][3]);
    }
    #pragma unroll
    for (int d=1; d<16; d<<=1){
      m0 = fmaxf(m0, __shfl_xor(m0,d)); m1 = fmaxf(m1, __shfl_xor(m1,d));
      m2 = fmaxf(m2, __shfl_xor(m2,d)); m3 = fmaxf(m3, __shfl_xor(m3,d));
    }
    float s0=0.f, s1=0.f, s2=0.f, s3=0.f;
    #pragma unroll
    for (int t=0;t<8;t++){
      float e0 = __expf(acc2[t][0]-m0); acc2[t][0]=e0; s0 += e0;
      float e1 = __expf(acc2[t][1]-m1); acc2[t][1]=e1; s1 += e1;
      float e2 = __expf(acc2[t][2]-m2); acc2[t][2]=e2; s2 += e2;
      float e3 = __expf(acc2[t][3]-m3); acc2[t][3]=e3; s3 += e3;
    }
    #pragma unroll
    for (int d=1; d<16; d<<=1){
      s0 += __shfl_xor(s0,d); s1 += __shfl_xor(s1,d);
      s2 += __shfl_xor(s2,d); s3 += __shfl_xor(s3,d);
    }
    float i0=1.f/s0, i1=1.f/s1, i2=1.f/s2, i3=1.f/s3;
    #pragma unroll
    for (int t=0;t<8;t++){
      a2p[t][0] = pk2(acc2[t][0]*i0, acc2[t][1]*i1);
      a2p[t][1] = pk2(acc2[t][2]*i2, acc2[t][3]*i3);
    }
  }

  __syncthreads();

  // ---- write A1 -> B3 (rm), A2T -> B2 (rm), VT -> B1 ----
  {
    int r = 16*w + lm;
    #pragma unroll
    for (int t=0;t<8;t++)
      *(uint2*)(B3 + r*256 + swz(r, t*32 + lq*8)) = make_uint2(a1p[t][0], a1p[t][1]);
  }
  #pragma unroll
  for (int t=0;t<8;t++){
    int jr = t*16 + lm;
    *(uint2*)(B2 + jr*256 + swz(jr, 32*w + lq*8)) = make_uint2(a2p[t][0], a2p[t][1]);
  }
  #pragma unroll
  for (int i=0;i<4;i++){
    int e = (tid + 512*i)*8;
    int row = e>>7, col = e&127;
    unsigned int vd[4] = {vreg[i].x, vreg[i].y, vreg[i].z, vreg[i].w};
    #pragma unroll
    for (int u=0;u<8;u++){
      unsigned short ve = (unsigned short)(vd[u>>1] >> (16*(u&1)));
      int tr = col + u;
      *(unsigned short*)(B1 + tr*256 + swz(tr, row*2)) = ve;
    }
  }
  __syncthreads();

  // ---- P3: MT = V^T * A1^T ----
  f32x4 acc3[8];
  #pragma unroll
  for (int t=0;t<8;t++) acc3[t] = (f32x4){0.f,0.f,0.f,0.f};
  {
    bf16x8 av[4];
    #pragma unroll
    for (int kk=0;kk<4;kk++){
      int jr = 16*w + lm;
      av[kk] = *(const bf16x8*)(B1 + jr*256 + swz(jr, kk*64 + lq*16));
    }
    #pragma unroll
    for (int kk=0;kk<4;kk++){
      #pragma unroll
      for (int rt=0;rt<8;rt++){
        int rr = rt*16 + lm;
        bf16x8 ba = *(const bf16x8*)(B3 + rr*256 + swz(rr, kk*64 + lq*16));
        acc3[rt] = __builtin_amdgcn_mfma_f32_16x16x32_bf16(av[kk], ba, acc3[rt], 0,0,0);
      }
    }
  }
  #pragma unroll
  for (int rt=0;rt<8;rt++){
    int rr = rt*16 + lm;
    unsigned int p0 = pk2(acc3[rt][0], acc3[rt][1]);
    unsigned int p1 = pk2(acc3[rt][2], acc3[rt][3]);
    *(uint2*)(B0 + rr*256 + swz(rr, 32*w + lq*8)) = make_uint2(p0, p1);
  }
  __syncthreads();

  // ---- P4: P = M * A2 -> global bf16 ----
  f32x4 acc4[8];
  #pragma unroll
  for (int t=0;t<8;t++) acc4[t] = (f32x4){0.f,0.f,0.f,0.f};
  {
    bf16x8 am[4];
    #pragma unroll
    for (int kk=0;kk<4;kk++){
      int rr = 16*w + lm;
      am[kk] = *(const bf16x8*)(B0 + rr*256 + swz(rr, kk*64 + lq*16));
    }
    #pragma unroll
    for (int kk=0;kk<4;kk++){
      #pragma unroll
      for (int ct=0;ct<8;ct++){
        int jr = ct*16 + lm;
        bf16x8 ba2 = *(const bf16x8*)(B2 + jr*256 + swz(jr, kk*64 + lq*16));
        acc4[ct] = __builtin_amdgcn_mfma_f32_16x16x32_bf16(am[kk], ba2, acc4[ct], 0,0,0);
      }
    }
  }
  unsigned short* pout = Pb + gbase;
  #pragma unroll
  for (int ct=0;ct<8;ct++){
    #pragma unroll
    for (int r4=0;r4<4;r4++){
      int rr = 16*w + lq*4 + r4;
      pout[rr*HH + ct*16 + lm] = f2bf(acc4[ct][r4]);
    }
  }
}

// ---------------- Kernel 3: out = relu(conv1x1(P, w3, b3)) fp32, MFMA -----
// 128-position tile, 25KB LDS -> 6 blocks/CU. fp32 scalar stores are already
// 64B-aligned runs per lane-quarter (no amplification) -> store direct.
__global__ __launch_bounds__(256, 6) void rc_conv_out(
    const unsigned short* __restrict__ Pb, const float* __restrict__ w3,
    const float* __restrict__ b3, float* __restrict__ out)
{
  __shared__ char smem[24832];
  char* Xs = smem;                     // 128 p-rows x 128 B
  char* Ws = smem + 16384;             // 64 o-rows x 128 B
  float* bias = (float*)(smem + 24576);

  const int tid = threadIdx.x;
  const int b  = blockIdx.y;
  const int pblock = blockIdx.x * 128;

  {
    int o = tid >> 2, c0 = (tid & 3) * 16;
    const float4* wr = (const float4*)(w3 + o*64 + c0);
    float4 f0 = wr[0], f1 = wr[1], f2v = wr[2], f3 = wr[3];
    uint4 pa, pb;
    pa.x = pk2(f0.x,f0.y);  pa.y = pk2(f0.z,f0.w);
    pa.z = pk2(f1.x,f1.y);  pa.w = pk2(f1.z,f1.w);
    pb.x = pk2(f2v.x,f2v.y); pb.y = pk2(f2v.z,f2v.w);
    pb.z = pk2(f3.x,f3.y);  pb.w = pk2(f3.z,f3.w);
    *(uint4*)(Ws + o*128 + swz(o, c0*2))      = pa;
    *(uint4*)(Ws + o*128 + swz(o, c0*2 + 16)) = pb;
  }
  if (tid < 64) bias[tid] = b3[tid];

  // ---- stage P tile: all 8 loads in flight, then pack to LDS ----
  const unsigned short* S = Pb + (size_t)b*NCH*NPOS + pblock;
  uint2 pr[2][4];
  #pragma unroll
  for (int g=0; g<2; ++g){
    int unit = tid + 256*g;
    int q  = unit >> 5;
    int p4 = (unit & 31) << 2;
    #pragma unroll
    for (int j=0;j<4;j++)
      pr[g][j] = *(const uint2*)(S + (size_t)(4*q+j)*NPOS + p4);
  }
  #pragma unroll
  for (int g=0; g<2; ++g){
    int unit = tid + 256*g;
    int q  = unit >> 5;
    int p4 = (unit & 31) << 2;
    const unsigned short* e0 = (const unsigned short*)&pr[g][0];
    const unsigned short* e1 = (const unsigned short*)&pr[g][1];
    const unsigned short* e2 = (const unsigned short*)&pr[g][2];
    const unsigned short* e3 = (const unsigned short*)&pr[g][3];
    #pragma unroll
    for (int u=0; u<4; ++u){
      uint2 pk;
      pk.x = (unsigned int)e0[u] | ((unsigned int)e1[u]<<16);
      pk.y = (unsigned int)e2[u] | ((unsigned int)e3[u]<<16);
      *(uint2*)(Xs + (p4+u)*128 + swz(p4+u, q*8)) = pk;
    }
  }
  __syncthreads();

  const int w = tid>>6, l = tid&63, lq = l>>4, lm = l&15;
  bf16x8 aW[2];
  {
    int orow = 16*w + lm;
    aW[0] = *(const bf16x8*)(Ws + orow*128 + swz(orow,      lq*16));
    aW[1] = *(const bf16x8*)(Ws + orow*128 + swz(orow, 64 + lq*16));
  }
  float bv[4];
  #pragma unroll
  for (int r4=0;r4<4;r4++) bv[r4] = bias[16*w + 4*lq + r4];

  float* dst = out + (size_t)b*NCH*NPOS;
  #pragma unroll
  for (int pt=0; pt<8; ++pt){
    int prow = pt*16 + lm;
    bf16x8 bx0 = *(const bf16x8*)(Xs + prow*128 + swz(prow,      lq*16));
    bf16x8 bx1 = *(const bf16x8*)(Xs + prow*128 + swz(prow, 64 + lq*16));
    f32x4 acc = (f32x4){0.f,0.f,0.f,0.f};
    acc = __builtin_amdgcn_mfma_f32_16x16x32_bf16(aW[0], bx0, acc, 0,0,0);
    acc = __builtin_amdgcn_mfma_f32_16x16x32_bf16(aW[1], bx1, acc, 0,0,0);
    int p = pblock + pt*16 + lm;
    #pragma unroll
    for (int r4=0;r4<4;r4++){
      int o = 16*w + 4*lq + r4;
      dst[(size_t)o*NPOS + p] = fmaxf(acc[r4] + bv[r4], 0.f);
    }
  }
}

extern "C" void kernel_launch(void* const* d_in, const int* in_sizes, int n_in,
                              void* d_out, int out_size, void* d_ws, size_t ws_size,
                              hipStream_t stream)
{
  const float* x   = (const float*)d_in[0];
  const float* att = (const float*)d_in[1];
  const float* w0  = (const float*)d_in[2]; const float* b0 = (const float*)d_in[3];
  const float* w1  = (const float*)d_in[4]; const float* b1 = (const float*)d_in[5];
  const float* w2  = (const float*)d_in[6]; const float* b2 = (const float*)d_in[7];
  const float* w3  = (const float*)d_in[8]; const float* b3 = (const float*)d_in[9];

  const size_t NM = (size_t)NB*NCH*NPOS;          // 16,777,216 elems per matrix
  unsigned short* Qb = (unsigned short*)d_ws;     // bf16, 33.55 MB each
  unsigned short* Kb = Qb + NM;
  unsigned short* Vb = Kb + NM;
  unsigned short* Pb = Vb + NM;
  float* out = (float*)d_out;

  (void)hipFuncSetAttribute((const void*)rc_attention_mfma,
                            hipFuncAttributeMaxDynamicSharedMemorySize, 131072);

  rc_conv_in<<<dim3(128, NB, 2), 256, 0, stream>>>(x, att, w0,b0, w1,b1, w2,b2,
                                                   Qb, Kb, Vb);

  rc_attention_mfma<<<dim3(NB*NCH), 512, 131072, stream>>>(Qb, Kb, Vb, Pb);

  rc_conv_out<<<dim3(128, NB), 256, 0, stream>>>(Pb, w3, b3, out);
}